// Round 3
// baseline (279.700 us; speedup 1.0000x reference)
//
#include <hip/hip_runtime.h>
#include <float.h>
#include <stdint.h>

#define N_TOK   65536
#define DIM     256
#define M_CODES 1024
#define CHUNK_CODES 64
#define N_CHUNKS (M_CODES / CHUNK_CODES)   // 16
#define BT      128
#define THR     2e-3f

typedef __attribute__((ext_vector_type(8))) short bf16x8;
typedef __attribute__((ext_vector_type(4))) float f32x4;

// round-to-nearest-even fp32 -> bf16 (finite inputs)
__device__ __forceinline__ unsigned short f2bf(float f) {
    unsigned u = __builtin_bit_cast(unsigned, f);
    unsigned r = (u + 0x7fffu + ((u >> 16) & 1u)) >> 16;
    return (unsigned short)r;
}

// ---------------- K0: embedding prep — e2 + frag-tiled bf16 copy ----------------
// eb HBM layout = MFMA-B-fragment order: for chunk(64 codes): for kk(8): for ct(4):
//   1024B frag, lane l=(g*16+cl) slot holds eb[code=chunk*64+ct*16+cl][k=kk*32+g*8 ..+7]
__global__ void prep_emb_kernel(const float* __restrict__ emb,
                                unsigned short* __restrict__ eb,
                                float* __restrict__ e2) {
    const int gid  = blockIdx.x * blockDim.x + threadIdx.x;
    const int code = gid >> 6;
    const int lane = gid & 63;
    if (code >= M_CODES) return;
    const float4 v = *reinterpret_cast<const float4*>(emb + (size_t)code * DIM + lane * 4);
    float s = __fmul_rn(v.x, v.x);
    s = __fadd_rn(s, __fmul_rn(v.y, v.y));
    s = __fadd_rn(s, __fmul_rn(v.z, v.z));
    s = __fadd_rn(s, __fmul_rn(v.w, v.w));
    #pragma unroll
    for (int off = 32; off; off >>= 1) s = __fadd_rn(s, __shfl_xor(s, off));

    const int d0 = lane * 4;
    const int chunk = code >> 6, ct = (code >> 4) & 3, cl = code & 15;
    const int kk = d0 >> 5, g = (d0 >> 3) & 3, j = d0 & 7;   // j in {0,4}
    ushort4 b4;
    b4.x = f2bf(v.x); b4.y = f2bf(v.y); b4.z = f2bf(v.z); b4.w = f2bf(v.w);
    const size_t dst = (size_t)chunk * 32768 + (size_t)(kk * 4 + ct) * 1024
                     + (size_t)(g * 16 + cl) * 16 + (size_t)j * 2;
    *reinterpret_cast<ushort4*>(reinterpret_cast<char*>(eb) + dst) = b4;
    if (lane == 0) e2[code] = s;
}

// ---------------- K1: bf16 MFMA prefilter -> per-token candidate set ----------------
// 4 waves x (32 tokens x 64 codes/chunk); A-frags (fp32 x -> bf16) resident in VGPRs;
// B-frags staged 32KB/chunk into LDS in fragment order (lane-linear ds_read_b128).
__global__ __launch_bounds__(256, 2) void prefilter_kernel(
    const float* __restrict__ x, const unsigned short* __restrict__ eb,
    const float* __restrict__ e2, unsigned int* __restrict__ cand)
{
    __shared__ char smem[36864];           // [0,32K): ebuf / merge; [32K,36K): e2s
    char*  ebuf = smem;
    float* e2s  = reinterpret_cast<float*>(smem + 32768);

    const int tid  = threadIdx.x;
    const int w    = tid >> 6, lane = tid & 63;
    const int cl   = lane & 15, g = lane >> 4;
    const int t0   = blockIdx.x * BT;

    e2s[tid]       = e2[tid];
    e2s[tid + 256] = e2[tid + 256];
    e2s[tid + 512] = e2[tid + 512];
    e2s[tid + 768] = e2[tid + 768];

    // A fragments: rows (w*32 + rt*16 + cl), k = kk*32 + g*8 .. +7
    bf16x8 afr[2][8];
    #pragma unroll
    for (int rt = 0; rt < 2; ++rt) {
        const float* xrow = x + (size_t)(t0 + w * 32 + rt * 16 + cl) * DIM + g * 8;
        #pragma unroll
        for (int kk = 0; kk < 8; ++kk) {
            const float4 lo = *reinterpret_cast<const float4*>(xrow + kk * 32);
            const float4 hi = *reinterpret_cast<const float4*>(xrow + kk * 32 + 4);
            bf16x8 a;
            a[0] = (short)f2bf(lo.x); a[1] = (short)f2bf(lo.y);
            a[2] = (short)f2bf(lo.z); a[3] = (short)f2bf(lo.w);
            a[4] = (short)f2bf(hi.x); a[5] = (short)f2bf(hi.y);
            a[6] = (short)f2bf(hi.z); a[7] = (short)f2bf(hi.w);
            afr[rt][kk] = a;
        }
    }

    // per-lane top-2 per owned row (8 rows: rt*4+reg); disjoint code classes (code%16==cl)
    float    tv0[8], tv1[8];
    unsigned ti0[8], ti1[8];
    #pragma unroll
    for (int r = 0; r < 8; ++r) { tv0[r] = FLT_MAX; tv1[r] = FLT_MAX; ti0[r] = 0; ti1[r] = 0; }

    float4 sreg[8];
    #pragma unroll
    for (int p = 0; p < 8; ++p)
        sreg[p] = *reinterpret_cast<const float4*>(
            reinterpret_cast<const char*>(eb) + (size_t)p * 4096 + (size_t)tid * 16);
    #pragma unroll
    for (int p = 0; p < 8; ++p)
        *reinterpret_cast<float4*>(ebuf + p * 4096 + tid * 16) = sreg[p];
    __syncthreads();

    for (int chunk = 0; chunk < N_CHUNKS; ++chunk) {
        if (chunk + 1 < N_CHUNKS) {          // issue next-chunk loads early (hide under MFMA)
            #pragma unroll
            for (int p = 0; p < 8; ++p)
                sreg[p] = *reinterpret_cast<const float4*>(
                    reinterpret_cast<const char*>(eb) + (size_t)(chunk + 1) * 32768
                    + (size_t)p * 4096 + (size_t)tid * 16);
        }
        const f32x4 z = {0.0f, 0.0f, 0.0f, 0.0f};
        f32x4 acc[2][4];
        #pragma unroll
        for (int rt = 0; rt < 2; ++rt)
            #pragma unroll
            for (int ct = 0; ct < 4; ++ct) acc[rt][ct] = z;

        #pragma unroll
        for (int kk = 0; kk < 8; ++kk) {
            #pragma unroll
            for (int ct = 0; ct < 4; ++ct) {
                const bf16x8 b = *reinterpret_cast<const bf16x8*>(
                    ebuf + ((kk * 4 + ct) << 10) + lane * 16);
                acc[0][ct] = __builtin_amdgcn_mfma_f32_16x16x32_bf16(afr[0][kk], b, acc[0][ct], 0, 0, 0);
                acc[1][ct] = __builtin_amdgcn_mfma_f32_16x16x32_bf16(afr[1][kk], b, acc[1][ct], 0, 0, 0);
            }
        }
        // prefilter score c = e2 - 2*S (x2 is per-token constant, irrelevant to argmin)
        const int cbase = chunk * CHUNK_CODES;
        #pragma unroll
        for (int ct = 0; ct < 4; ++ct) {
            const unsigned code = (unsigned)(cbase + ct * 16 + cl);
            const float e2v = e2s[code];
            #pragma unroll
            for (int rt = 0; rt < 2; ++rt)
                #pragma unroll
                for (int q = 0; q < 4; ++q) {
                    const float c = e2v - 2.0f * acc[rt][ct][q];
                    const int r = rt * 4 + q;
                    if (c < tv1[r]) {
                        if (c < tv0[r]) { tv1[r] = tv0[r]; ti1[r] = ti0[r]; tv0[r] = c; ti0[r] = code; }
                        else            { tv1[r] = c; ti1[r] = code; }
                    }
                }
        }
        __syncthreads();                      // all waves done reading ebuf
        if (chunk + 1 < N_CHUNKS) {
            #pragma unroll
            for (int p = 0; p < 8; ++p)
                *reinterpret_cast<float4*>(ebuf + p * 4096 + tid * 16) = sreg[p];
        }
        __syncthreads();                      // staged data visible
    }

    // merge: 16 lanes x top-2 = 32 entries per token (alias ebuf region)
    float*    mv = reinterpret_cast<float*>(smem);            // [128][32]
    unsigned* mi = reinterpret_cast<unsigned*>(smem + 16384); // [128][32]
    #pragma unroll
    for (int r = 0; r < 8; ++r) {
        const int rt = r >> 2, q = r & 3;
        const int row = w * 32 + rt * 16 + g * 4 + q;   // C/D: row=(lane>>4)*4+reg, col=lane&15
        mv[row * 32 + cl * 2 + 0] = tv0[r];  mi[row * 32 + cl * 2 + 0] = ti0[r];
        mv[row * 32 + cl * 2 + 1] = tv1[r];  mi[row * 32 + cl * 2 + 1] = ti1[r];
    }
    __syncthreads();
    if (tid < BT) {
        const float*    v  = mv + tid * 32;
        const unsigned* ii = mi + tid * 32;
        float vmin = v[0]; unsigned imin = ii[0];
        for (int j2 = 1; j2 < 32; ++j2) {
            const float vv = v[j2]; const unsigned ij = ii[j2];
            if (vv < vmin || (vv == vmin && ij < imin)) { vmin = vv; imin = ij; }
        }
        unsigned lst[7]; lst[0] = imin; int cnt = 1;
        const float lim = vmin + THR;
        for (int j2 = 0; j2 < 32; ++j2) {
            const unsigned ij = ii[j2];
            if (v[j2] <= lim && ij != imin && cnt < 7) lst[cnt++] = ij;
        }
        unsigned* cp = cand + (size_t)(t0 + tid) * 8;
        cp[0] = (unsigned)cnt;
        #pragma unroll
        for (int j2 = 0; j2 < 7; ++j2) cp[1 + j2] = (j2 < cnt) ? lst[j2] : imin;
    }
}

// ---------------- K2: exact fp32 rescue + gather + straight-through + commit ----------------
__global__ __launch_bounds__(256) void rescue_kernel(
    const float* __restrict__ x, const float* __restrict__ emb,
    const float* __restrict__ e2, const unsigned* __restrict__ cand,
    float* __restrict__ out_q, float* __restrict__ out_inds,
    unsigned* __restrict__ counts, float* __restrict__ cparts)
{
    const int tid = threadIdx.x, w = tid >> 6, lane = tid & 63;
    const int t = blockIdx.x * 4 + w;

    const float4 xv = *reinterpret_cast<const float4*>(x + (size_t)t * DIM + lane * 4);
    float s = __fmul_rn(xv.x, xv.x);
    s = __fadd_rn(s, __fmul_rn(xv.y, xv.y));
    s = __fadd_rn(s, __fmul_rn(xv.z, xv.z));
    s = __fadd_rn(s, __fmul_rn(xv.w, xv.w));
    #pragma unroll
    for (int off = 32; off; off >>= 1) s = __fadd_rn(s, __shfl_xor(s, off));
    const float x2t = s;

    const unsigned* cp = cand + (size_t)t * 8;
    const int cnt = min((int)cp[0], 7);
    float bd = FLT_MAX; unsigned bi = 0xFFFFFFFFu;
    for (int cix = 0; cix < cnt; ++cix) {
        const unsigned ci = cp[1 + cix];
        const float4 ev = *reinterpret_cast<const float4*>(emb + (size_t)ci * DIM + lane * 4);
        float p = __fmul_rn(xv.x, ev.x);
        p = fmaf(xv.y, ev.y, p);
        p = fmaf(xv.z, ev.z, p);
        p = fmaf(xv.w, ev.w, p);
        #pragma unroll
        for (int off = 32; off; off >>= 1) p = __fadd_rn(p, __shfl_xor(p, off));
        const float d = __fsub_rn(__fadd_rn(e2[ci], x2t), __fmul_rn(2.0f, p));
        if (d < bd || (d == bd && ci < bi)) { bd = d; bi = ci; }
    }

    const float4 qv = *reinterpret_cast<const float4*>(emb + (size_t)bi * DIM + lane * 4);
    float4 o;
    o.x = __fadd_rn(xv.x, __fsub_rn(qv.x, xv.x));
    o.y = __fadd_rn(xv.y, __fsub_rn(qv.y, xv.y));
    o.z = __fadd_rn(xv.z, __fsub_rn(qv.z, xv.z));
    o.w = __fadd_rn(xv.w, __fsub_rn(qv.w, xv.w));
    *reinterpret_cast<float4*>(out_q + (size_t)t * DIM + lane * 4) = o;

    float cl2 = 0.0f, dx;
    dx = __fsub_rn(xv.x, qv.x); cl2 = fmaf(dx, dx, cl2);
    dx = __fsub_rn(xv.y, qv.y); cl2 = fmaf(dx, dx, cl2);
    dx = __fsub_rn(xv.z, qv.z); cl2 = fmaf(dx, dx, cl2);
    dx = __fsub_rn(xv.w, qv.w); cl2 = fmaf(dx, dx, cl2);
    #pragma unroll
    for (int off = 32; off; off >>= 1) cl2 += __shfl_xor(cl2, off);

    __shared__ float wp[4];
    if (lane == 0) {
        out_inds[t] = (float)bi;
        atomicAdd(&counts[bi], 1u);
        wp[w] = cl2;
    }
    __syncthreads();
    if (tid == 0) cparts[blockIdx.x] = (wp[0] + wp[1]) + (wp[2] + wp[3]);
}

// ---------------- K3: stats scalars ----------------
__global__ void stats_kernel(const unsigned* __restrict__ counts,
                             const float* __restrict__ cparts,
                             float* __restrict__ out)
{
    const int tid = threadIdx.x, lane = tid & 63, wv = tid >> 6;  // 1024 threads
    const float c = (float)counts[tid];
    float u = (c >= 1.0f) ? 1.0f : 0.0f;
    const float p = c / 65536.0f;
    float e = p * logf(p + 1e-10f);
    double cs = 0.0;
    #pragma unroll
    for (int j = 0; j < 16; ++j) cs += (double)cparts[tid * 16 + j];
    #pragma unroll
    for (int off = 32; off; off >>= 1) {
        u  += __shfl_xor(u, off);
        e  += __shfl_xor(e, off);
        cs += __shfl_xor(cs, off);
    }
    __shared__ float  su[16], se[16];
    __shared__ double sc[16];
    if (lane == 0) { su[wv] = u; se[wv] = e; sc[wv] = cs; }
    __syncthreads();
    if (tid == 0) {
        float U = 0.0f, E = 0.0f; double C = 0.0;
        for (int wj = 0; wj < 16; ++wj) { U += su[wj]; E += se[wj]; C += sc[wj]; }
        out[16842752] = U;
        out[16842753] = expf(-E);
        out[16842754] = (float)(C / 16777216.0);
    }
}

extern "C" void kernel_launch(void* const* d_in, const int* in_sizes, int n_in,
                              void* d_out, int out_size, void* d_ws, size_t ws_size,
                              hipStream_t stream) {
    const float* x   = (const float*)d_in[0];
    const float* emb = (const float*)d_in[1];
    float* out = (float*)d_out;

    char* ws = (char*)d_ws;
    float*          e2     = (float*)ws;                        // 4 KB
    unsigned short* eb     = (unsigned short*)(ws + 4096);      // 512 KB (frag-tiled bf16)
    unsigned*       cand   = (unsigned*)(ws + 528384);          // 2 MB  (8 u32 / token)
    unsigned*       counts = (unsigned*)(ws + 2625536);         // 4 KB
    float*          cparts = (float*)(ws + 2629632);            // 64 KB (16384 f32)

    float* out_q    = out;                   // [0, 16777216)
    float* out_inds = out + 16777216;        // [16777216, 16842752)

    hipMemsetAsync(counts, 0, 4096, stream);

    prep_emb_kernel<<<256, 256, 0, stream>>>(emb, eb, e2);
    prefilter_kernel<<<N_TOK / BT, 256, 0, stream>>>(x, eb, e2, cand);
    rescue_kernel<<<N_TOK / 4, 256, 0, stream>>>(x, emb, e2, cand, out_q, out_inds, counts, cparts);
    stats_kernel<<<1, 1024, 0, stream>>>(counts, cparts, out);
}

// Round 4
// 228.705 us; speedup vs baseline: 1.2230x; 1.2230x over previous
//
#include <hip/hip_runtime.h>
#include <float.h>
#include <stdint.h>

#define N_TOK   65536
#define DIM     256
#define M_CODES 1024
#define CHUNK_CODES 32
#define N_CHUNKS (M_CODES / CHUNK_CODES)   // 32
#define CHUNK_BYTES 16384                  // 32 codes x 256 k x 2B
#define BT      128
#define THR     2e-3f

typedef __attribute__((ext_vector_type(8))) short bf16x8;
typedef __attribute__((ext_vector_type(4))) float f32x4;

// round-to-nearest-even fp32 -> bf16 (finite inputs)
__device__ __forceinline__ unsigned short f2bf(float f) {
    unsigned u = __builtin_bit_cast(unsigned, f);
    unsigned r = (u + 0x7fffu + ((u >> 16) & 1u)) >> 16;
    return (unsigned short)r;
}

// direct HBM -> LDS, 16B per lane, no VGPR round-trip (kills the sreg spill)
__device__ __forceinline__ void gload_lds16(const void* g, void* l) {
    __builtin_amdgcn_global_load_lds(
        (const __attribute__((address_space(1))) unsigned int*)g,
        (__attribute__((address_space(3))) unsigned int*)l, 16, 0, 0);
}

// ---------------- K0: embedding prep — e2 + frag-tiled bf16 copy ----------------
// eb layout = MFMA-B-fragment order per 32-code chunk: for chunk(32 codes): for kk(8):
// for ct(2): 1024B frag; lane l=(g*16+cl) slot holds eb[code=chunk*32+ct*16+cl][k=kk*32+g*8..+7]
__global__ void prep_emb_kernel(const float* __restrict__ emb,
                                unsigned short* __restrict__ eb,
                                float* __restrict__ e2) {
    const int gid  = blockIdx.x * blockDim.x + threadIdx.x;
    const int code = gid >> 6;
    const int lane = gid & 63;
    if (code >= M_CODES) return;
    const float4 v = *reinterpret_cast<const float4*>(emb + (size_t)code * DIM + lane * 4);
    float s = __fmul_rn(v.x, v.x);
    s = __fadd_rn(s, __fmul_rn(v.y, v.y));
    s = __fadd_rn(s, __fmul_rn(v.z, v.z));
    s = __fadd_rn(s, __fmul_rn(v.w, v.w));
    #pragma unroll
    for (int off = 32; off; off >>= 1) s = __fadd_rn(s, __shfl_xor(s, off));

    const int d0 = lane * 4;
    const int chunk = code >> 5, ct = (code >> 4) & 1, cl = code & 15;
    const int kk = d0 >> 5, g = (d0 >> 3) & 3, j = d0 & 7;   // j in {0,4}
    ushort4 b4;
    b4.x = f2bf(v.x); b4.y = f2bf(v.y); b4.z = f2bf(v.z); b4.w = f2bf(v.w);
    const size_t dst = (size_t)chunk * CHUNK_BYTES + (size_t)(kk * 2 + ct) * 1024
                     + (size_t)(g * 16 + cl) * 16 + (size_t)j * 2;
    *reinterpret_cast<ushort4*>(reinterpret_cast<char*>(eb) + dst) = b4;
    if (lane == 0) e2[code] = s;
}

// ---------------- K1: bf16 MFMA prefilter -> per-token candidate set ----------------
// 4 waves x (32 tokens x 32 codes/chunk); A-frags resident in VGPRs; B-frags double-
// buffered via global_load_lds (lane-linear frag layout -> legal wave-uniform dest).
__global__ __launch_bounds__(256, 2) void prefilter_kernel(
    const float* __restrict__ x, const unsigned short* __restrict__ eb,
    const float* __restrict__ e2, unsigned int* __restrict__ cand)
{
    __shared__ char smem[2 * CHUNK_BYTES + 4096];   // 36 KB: dbuf + e2s
    float* e2s = reinterpret_cast<float*>(smem + 2 * CHUNK_BYTES);

    const int tid  = threadIdx.x;
    const int w    = tid >> 6, lane = tid & 63;
    const int cl   = lane & 15, g = lane >> 4;
    const int t0   = blockIdx.x * BT;

    e2s[tid]       = e2[tid];
    e2s[tid + 256] = e2[tid + 256];
    e2s[tid + 512] = e2[tid + 512];
    e2s[tid + 768] = e2[tid + 768];

    // stage chunk 0 into buf0 (4 x 16B per thread, lane-linear)
    {
        const char* src = reinterpret_cast<const char*>(eb) + (size_t)tid * 16;
        #pragma unroll
        for (int p = 0; p < 4; ++p)
            gload_lds16(src + p * 4096, smem + p * 4096 + tid * 16);
    }

    // A fragments: rows (w*32 + rt*16 + cl), k = kk*32 + g*8 .. +7  (validated mapping)
    bf16x8 afr[2][8];
    #pragma unroll
    for (int rt = 0; rt < 2; ++rt) {
        const float* xrow = x + (size_t)(t0 + w * 32 + rt * 16 + cl) * DIM + g * 8;
        #pragma unroll
        for (int kk = 0; kk < 8; ++kk) {
            const float4 lo = *reinterpret_cast<const float4*>(xrow + kk * 32);
            const float4 hi = *reinterpret_cast<const float4*>(xrow + kk * 32 + 4);
            bf16x8 a;
            a[0] = (short)f2bf(lo.x); a[1] = (short)f2bf(lo.y);
            a[2] = (short)f2bf(lo.z); a[3] = (short)f2bf(lo.w);
            a[4] = (short)f2bf(hi.x); a[5] = (short)f2bf(hi.y);
            a[6] = (short)f2bf(hi.z); a[7] = (short)f2bf(hi.w);
            afr[rt][kk] = a;
        }
    }

    // per-lane top-2 per owned row; disjoint code classes (code%16==cl)
    float    tv0[8], tv1[8];
    unsigned ti0[8], ti1[8];
    #pragma unroll
    for (int r = 0; r < 8; ++r) { tv0[r] = FLT_MAX; tv1[r] = FLT_MAX; ti0[r] = 0; ti1[r] = 0; }

    asm volatile("s_waitcnt vmcnt(0)");
    __syncthreads();

    for (int chunk = 0; chunk < N_CHUNKS; ++chunk) {
        char* cb_ = smem + ((chunk & 1) ? CHUNK_BYTES : 0);
        char* nb_ = smem + ((chunk & 1) ? 0 : CHUNK_BYTES);
        if (chunk + 1 < N_CHUNKS) {   // issue next-chunk HBM->LDS early; hides under MFMA
            const char* src = reinterpret_cast<const char*>(eb)
                            + (size_t)(chunk + 1) * CHUNK_BYTES + (size_t)tid * 16;
            #pragma unroll
            for (int p = 0; p < 4; ++p)
                gload_lds16(src + p * 4096, nb_ + p * 4096 + tid * 16);
        }

        const f32x4 z = {0.0f, 0.0f, 0.0f, 0.0f};
        f32x4 acc[2][2];
        acc[0][0] = z; acc[0][1] = z; acc[1][0] = z; acc[1][1] = z;

        #pragma unroll
        for (int kk = 0; kk < 8; ++kk) {
            #pragma unroll
            for (int ct = 0; ct < 2; ++ct) {
                const bf16x8 b = *reinterpret_cast<const bf16x8*>(
                    cb_ + ((kk * 2 + ct) << 10) + lane * 16);
                acc[0][ct] = __builtin_amdgcn_mfma_f32_16x16x32_bf16(afr[0][kk], b, acc[0][ct], 0, 0, 0);
                acc[1][ct] = __builtin_amdgcn_mfma_f32_16x16x32_bf16(afr[1][kk], b, acc[1][ct], 0, 0, 0);
            }
        }

        // prefilter score c = e2 - 2*S (x2 is a per-token constant, irrelevant to argmin)
        const int cbase = chunk * CHUNK_CODES;
        #pragma unroll
        for (int ct = 0; ct < 2; ++ct) {
            const unsigned code = (unsigned)(cbase + ct * 16 + cl);
            const float e2v = e2s[code];
            #pragma unroll
            for (int rt = 0; rt < 2; ++rt)
                #pragma unroll
                for (int q = 0; q < 4; ++q) {
                    const float c = e2v - 2.0f * acc[rt][ct][q];
                    const int r = rt * 4 + q;
                    if (c < tv1[r]) {
                        if (c < tv0[r]) { tv1[r] = tv0[r]; ti1[r] = ti0[r]; tv0[r] = c; ti0[r] = code; }
                        else            { tv1[r] = c; ti1[r] = code; }
                    }
                }
        }
        __syncthreads();   // compiler drains vmcnt before barrier -> nb_ staged & visible
    }

    // merge: 16 lanes x top-2 = 32 entries per token; stride 33 = conflict-free
    float*    mv = reinterpret_cast<float*>(smem);             // [128][33]
    unsigned* mi = reinterpret_cast<unsigned*>(smem + 16896);  // [128][33]
    #pragma unroll
    for (int r = 0; r < 8; ++r) {
        const int rt = r >> 2, q = r & 3;
        const int row = w * 32 + rt * 16 + g * 4 + q;   // C/D: row=(lane>>4)*4+reg, col=lane&15
        mv[row * 33 + cl * 2 + 0] = tv0[r];  mi[row * 33 + cl * 2 + 0] = ti0[r];
        mv[row * 33 + cl * 2 + 1] = tv1[r];  mi[row * 33 + cl * 2 + 1] = ti1[r];
    }
    __syncthreads();
    if (tid < BT) {
        const float*    v  = mv + tid * 33;
        const unsigned* ii = mi + tid * 33;
        float vmin = v[0]; unsigned imin = ii[0];
        for (int j2 = 1; j2 < 32; ++j2) {
            const float vv = v[j2]; const unsigned ij = ii[j2];
            if (vv < vmin || (vv == vmin && ij < imin)) { vmin = vv; imin = ij; }
        }
        unsigned lst[7]; lst[0] = imin; int cnt = 1;
        const float lim = vmin + THR;
        for (int j2 = 0; j2 < 32; ++j2) {
            const unsigned ij = ii[j2];
            if (v[j2] <= lim && ij != imin && cnt < 7) lst[cnt++] = ij;
        }
        unsigned* cp = cand + (size_t)(t0 + tid) * 8;
        cp[0] = (unsigned)cnt;
        #pragma unroll
        for (int j2 = 0; j2 < 7; ++j2) cp[1 + j2] = (j2 < cnt) ? lst[j2] : imin;
    }
}

// ---------------- K2: exact fp32 rescue + gather + straight-through + commit ----------------
__global__ __launch_bounds__(256) void rescue_kernel(
    const float* __restrict__ x, const float* __restrict__ emb,
    const float* __restrict__ e2, const unsigned* __restrict__ cand,
    float* __restrict__ out_q, float* __restrict__ out_inds,
    unsigned* __restrict__ counts, float* __restrict__ cparts)
{
    const int tid = threadIdx.x, w = tid >> 6, lane = tid & 63;
    const int t = blockIdx.x * 4 + w;

    const float4 xv = *reinterpret_cast<const float4*>(x + (size_t)t * DIM + lane * 4);
    float s = __fmul_rn(xv.x, xv.x);
    s = __fadd_rn(s, __fmul_rn(xv.y, xv.y));
    s = __fadd_rn(s, __fmul_rn(xv.z, xv.z));
    s = __fadd_rn(s, __fmul_rn(xv.w, xv.w));
    #pragma unroll
    for (int off = 32; off; off >>= 1) s = __fadd_rn(s, __shfl_xor(s, off));
    const float x2t = s;

    const unsigned* cp = cand + (size_t)t * 8;
    const int cnt = min((int)cp[0], 7);
    float bd = FLT_MAX; unsigned bi = 0xFFFFFFFFu;
    for (int cix = 0; cix < cnt; ++cix) {
        const unsigned ci = cp[1 + cix];
        const float4 ev = *reinterpret_cast<const float4*>(emb + (size_t)ci * DIM + lane * 4);
        float p = __fmul_rn(xv.x, ev.x);
        p = fmaf(xv.y, ev.y, p);
        p = fmaf(xv.z, ev.z, p);
        p = fmaf(xv.w, ev.w, p);
        #pragma unroll
        for (int off = 32; off; off >>= 1) p = __fadd_rn(p, __shfl_xor(p, off));
        const float d = __fsub_rn(__fadd_rn(e2[ci], x2t), __fmul_rn(2.0f, p));
        if (d < bd || (d == bd && ci < bi)) { bd = d; bi = ci; }
    }

    const float4 qv = *reinterpret_cast<const float4*>(emb + (size_t)bi * DIM + lane * 4);
    float4 o;
    o.x = __fadd_rn(xv.x, __fsub_rn(qv.x, xv.x));
    o.y = __fadd_rn(xv.y, __fsub_rn(qv.y, xv.y));
    o.z = __fadd_rn(xv.z, __fsub_rn(qv.z, xv.z));
    o.w = __fadd_rn(xv.w, __fsub_rn(qv.w, xv.w));
    *reinterpret_cast<float4*>(out_q + (size_t)t * DIM + lane * 4) = o;

    float cl2 = 0.0f, dx;
    dx = __fsub_rn(xv.x, qv.x); cl2 = fmaf(dx, dx, cl2);
    dx = __fsub_rn(xv.y, qv.y); cl2 = fmaf(dx, dx, cl2);
    dx = __fsub_rn(xv.z, qv.z); cl2 = fmaf(dx, dx, cl2);
    dx = __fsub_rn(xv.w, qv.w); cl2 = fmaf(dx, dx, cl2);
    #pragma unroll
    for (int off = 32; off; off >>= 1) cl2 += __shfl_xor(cl2, off);

    __shared__ float wp[4];
    if (lane == 0) {
        out_inds[t] = (float)bi;
        atomicAdd(&counts[bi], 1u);
        wp[w] = cl2;
    }
    __syncthreads();
    if (tid == 0) cparts[blockIdx.x] = (wp[0] + wp[1]) + (wp[2] + wp[3]);
}

// ---------------- K3: stats scalars ----------------
__global__ void stats_kernel(const unsigned* __restrict__ counts,
                             const float* __restrict__ cparts,
                             float* __restrict__ out)
{
    const int tid = threadIdx.x, lane = tid & 63, wv = tid >> 6;  // 1024 threads
    const float c = (float)counts[tid];
    float u = (c >= 1.0f) ? 1.0f : 0.0f;
    const float p = c / 65536.0f;
    float e = p * logf(p + 1e-10f);
    double cs = 0.0;
    #pragma unroll
    for (int j = 0; j < 16; ++j) cs += (double)cparts[tid * 16 + j];
    #pragma unroll
    for (int off = 32; off; off >>= 1) {
        u  += __shfl_xor(u, off);
        e  += __shfl_xor(e, off);
        cs += __shfl_xor(cs, off);
    }
    __shared__ float  su[16], se[16];
    __shared__ double sc[16];
    if (lane == 0) { su[wv] = u; se[wv] = e; sc[wv] = cs; }
    __syncthreads();
    if (tid == 0) {
        float U = 0.0f, E = 0.0f; double C = 0.0;
        for (int wj = 0; wj < 16; ++wj) { U += su[wj]; E += se[wj]; C += sc[wj]; }
        out[16842752] = U;
        out[16842753] = expf(-E);
        out[16842754] = (float)(C / 16777216.0);
    }
}

extern "C" void kernel_launch(void* const* d_in, const int* in_sizes, int n_in,
                              void* d_out, int out_size, void* d_ws, size_t ws_size,
                              hipStream_t stream) {
    const float* x   = (const float*)d_in[0];
    const float* emb = (const float*)d_in[1];
    float* out = (float*)d_out;

    char* ws = (char*)d_ws;
    float*          e2     = (float*)ws;                        // 4 KB
    unsigned short* eb     = (unsigned short*)(ws + 4096);      // 512 KB (frag-tiled bf16)
    unsigned*       cand   = (unsigned*)(ws + 528384);          // 2 MB  (8 u32 / token)
    unsigned*       counts = (unsigned*)(ws + 2625536);         // 4 KB
    float*          cparts = (float*)(ws + 2629632);            // 64 KB (16384 f32)

    float* out_q    = out;                   // [0, 16777216)
    float* out_inds = out + 16777216;        // [16777216, 16842752)

    hipMemsetAsync(counts, 0, 4096, stream);

    prep_emb_kernel<<<256, 256, 0, stream>>>(emb, eb, e2);
    prefilter_kernel<<<N_TOK / BT, 256, 0, stream>>>(x, eb, e2, cand);
    rescue_kernel<<<N_TOK / 4, 256, 0, stream>>>(x, emb, e2, cand, out_q, out_inds, counts, cparts);
    stats_kernel<<<1, 1024, 0, stream>>>(counts, cparts, out);
}

// Round 5
// 213.589 us; speedup vs baseline: 1.3095x; 1.0708x over previous
//
#include <hip/hip_runtime.h>
#include <float.h>
#include <stdint.h>

#define N_TOK   65536
#define DIM     256
#define M_CODES 1024
#define CHUNK_CODES 32
#define N_CHUNKS (M_CODES / CHUNK_CODES)   // 32
#define CHUNK_BYTES 16384                  // 32 codes x 256 k x 2B
#define BT      128
#define THR     2e-3f

typedef __attribute__((ext_vector_type(8))) short bf16x8;
typedef __attribute__((ext_vector_type(4))) float f32x4;

// round-to-nearest-even fp32 -> bf16 (finite inputs)
__device__ __forceinline__ unsigned short f2bf(float f) {
    unsigned u = __builtin_bit_cast(unsigned, f);
    unsigned r = (u + 0x7fffu + ((u >> 16) & 1u)) >> 16;
    return (unsigned short)r;
}

// direct HBM -> LDS, 16B per lane, no VGPR round-trip
__device__ __forceinline__ void gload_lds16(const void* g, void* l) {
    __builtin_amdgcn_global_load_lds(
        (const __attribute__((address_space(1))) unsigned int*)g,
        (__attribute__((address_space(3))) unsigned int*)l, 16, 0, 0);
}

// ---------------- K0: embedding prep — e2 + frag-tiled bf16 copy + counts zero ----------------
// eb layout = MFMA-B-fragment order per 32-code chunk: for chunk(32 codes): for kk(8):
// for ct(2): 1024B frag; lane l=(g*16+cl) slot holds eb[code=chunk*32+ct*16+cl][k=kk*32+g*8..+7]
__global__ void prep_emb_kernel(const float* __restrict__ emb,
                                unsigned short* __restrict__ eb,
                                float* __restrict__ e2,
                                unsigned* __restrict__ counts) {
    const int gid  = blockIdx.x * blockDim.x + threadIdx.x;
    if (gid < M_CODES) counts[gid] = 0u;
    const int code = gid >> 6;
    const int lane = gid & 63;
    if (code >= M_CODES) return;
    const float4 v = *reinterpret_cast<const float4*>(emb + (size_t)code * DIM + lane * 4);
    float s = __fmul_rn(v.x, v.x);
    s = __fadd_rn(s, __fmul_rn(v.y, v.y));
    s = __fadd_rn(s, __fmul_rn(v.z, v.z));
    s = __fadd_rn(s, __fmul_rn(v.w, v.w));
    #pragma unroll
    for (int off = 32; off; off >>= 1) s = __fadd_rn(s, __shfl_xor(s, off));

    const int d0 = lane * 4;
    const int chunk = code >> 5, ct = (code >> 4) & 1, cl = code & 15;
    const int kk = d0 >> 5, g = (d0 >> 3) & 3, j = d0 & 7;   // j in {0,4}
    ushort4 b4;
    b4.x = f2bf(v.x); b4.y = f2bf(v.y); b4.z = f2bf(v.z); b4.w = f2bf(v.w);
    const size_t dst = (size_t)chunk * CHUNK_BYTES + (size_t)(kk * 2 + ct) * 1024
                     + (size_t)(g * 16 + cl) * 16 + (size_t)j * 2;
    *reinterpret_cast<ushort4*>(reinterpret_cast<char*>(eb) + dst) = b4;
    if (lane == 0) e2[code] = s;
}

// ---------------- K1: bf16 MFMA prefilter -> per-token candidate set ----------------
// 3-buffer LDS ring, counted vmcnt (never drained in-loop), raw s_barrier.
__global__ __launch_bounds__(256, 2) void prefilter_kernel(
    const float* __restrict__ x, const unsigned short* __restrict__ eb,
    const float* __restrict__ e2, unsigned int* __restrict__ cand)
{
    __shared__ char smem[3 * CHUNK_BYTES + 4096];   // 52 KB: ring + e2s
    float* e2s = reinterpret_cast<float*>(smem + 3 * CHUNK_BYTES);

    const int tid  = threadIdx.x;
    const int w    = tid >> 6, lane = tid & 63;
    const int cl   = lane & 15, g = lane >> 4;
    const int t0   = blockIdx.x * BT;

    // issue chunk 0,1 stages first (latency hidden under A-frag setup)
    {
        const char* s0 = reinterpret_cast<const char*>(eb) + (size_t)tid * 16;
        #pragma unroll
        for (int p = 0; p < 4; ++p)
            gload_lds16(s0 + p * 4096, smem + p * 4096 + tid * 16);
        const char* s1 = s0 + CHUNK_BYTES;
        #pragma unroll
        for (int p = 0; p < 4; ++p)
            gload_lds16(s1 + p * 4096, smem + CHUNK_BYTES + p * 4096 + tid * 16);
    }

    // A fragments: rows (w*32 + rt*16 + cl), k = kk*32 + g*8 .. +7  (validated mapping)
    bf16x8 afr[2][8];
    #pragma unroll
    for (int rt = 0; rt < 2; ++rt) {
        const float* xrow = x + (size_t)(t0 + w * 32 + rt * 16 + cl) * DIM + g * 8;
        #pragma unroll
        for (int kk = 0; kk < 8; ++kk) {
            const float4 lo = *reinterpret_cast<const float4*>(xrow + kk * 32);
            const float4 hi = *reinterpret_cast<const float4*>(xrow + kk * 32 + 4);
            bf16x8 a;
            a[0] = (short)f2bf(lo.x); a[1] = (short)f2bf(lo.y);
            a[2] = (short)f2bf(lo.z); a[3] = (short)f2bf(lo.w);
            a[4] = (short)f2bf(hi.x); a[5] = (short)f2bf(hi.y);
            a[6] = (short)f2bf(hi.z); a[7] = (short)f2bf(hi.w);
            afr[rt][kk] = a;
        }
    }

    e2s[tid]       = e2[tid];
    e2s[tid + 256] = e2[tid + 256];
    e2s[tid + 512] = e2[tid + 512];
    e2s[tid + 768] = e2[tid + 768];
    asm volatile("s_waitcnt lgkmcnt(0)" ::: "memory");   // e2s visible before first barrier

    float    tv0[8], tv1[8];
    unsigned ti0[8], ti1[8];
    #pragma unroll
    for (int r = 0; r < 8; ++r) { tv0[r] = FLT_MAX; tv1[r] = FLT_MAX; ti0[r] = 0; ti1[r] = 0; }

    char* bA = smem;                      // current
    char* bB = smem + CHUNK_BYTES;        // next
    char* bC = smem + 2 * CHUNK_BYTES;    // staging target

    auto compute = [&](int chunk, const char* cb_) {
        const f32x4 z = {0.0f, 0.0f, 0.0f, 0.0f};
        f32x4 acc[2][2];
        acc[0][0] = z; acc[0][1] = z; acc[1][0] = z; acc[1][1] = z;
        #pragma unroll
        for (int kk = 0; kk < 8; ++kk) {
            #pragma unroll
            for (int ct = 0; ct < 2; ++ct) {
                const bf16x8 b = *reinterpret_cast<const bf16x8*>(
                    cb_ + ((kk * 2 + ct) << 10) + lane * 16);
                acc[0][ct] = __builtin_amdgcn_mfma_f32_16x16x32_bf16(afr[0][kk], b, acc[0][ct], 0, 0, 0);
                acc[1][ct] = __builtin_amdgcn_mfma_f32_16x16x32_bf16(afr[1][kk], b, acc[1][ct], 0, 0, 0);
            }
        }
        // prefilter score c = e2 - 2*S (x2 is per-token constant, irrelevant to argmin)
        const int cbase = chunk * CHUNK_CODES;
        #pragma unroll
        for (int ct = 0; ct < 2; ++ct) {
            const unsigned code = (unsigned)(cbase + ct * 16 + cl);
            const float e2v = e2s[code];
            #pragma unroll
            for (int rt = 0; rt < 2; ++rt)
                #pragma unroll
                for (int q = 0; q < 4; ++q) {
                    const float c = e2v - 2.0f * acc[rt][ct][q];
                    const int r = rt * 4 + q;
                    if (c < tv1[r]) {
                        if (c < tv0[r]) { tv1[r] = tv0[r]; ti1[r] = ti0[r]; tv0[r] = c; ti0[r] = code; }
                        else            { tv1[r] = c; ti1[r] = code; }
                    }
                }
        }
    };

    for (int chunk = 0; chunk < N_CHUNKS - 1; ++chunk) {
        // ensure current chunk staged: allow the 4 next-chunk loads to stay in flight
        asm volatile("s_waitcnt vmcnt(4)" ::: "memory");
        __builtin_amdgcn_s_barrier();
        __builtin_amdgcn_sched_barrier(0);
        if (chunk + 2 < N_CHUNKS) {       // stage chunk+2 into bC (safe: all waves past barrier)
            const char* src = reinterpret_cast<const char*>(eb)
                            + (size_t)(chunk + 2) * CHUNK_BYTES + (size_t)tid * 16;
            #pragma unroll
            for (int p = 0; p < 4; ++p)
                gload_lds16(src + p * 4096, bC + p * 4096 + tid * 16);
        }
        __builtin_amdgcn_sched_barrier(0);
        compute(chunk, bA);
        char* t_ = bA; bA = bB; bB = bC; bC = t_;   // rotate ring
    }
    // peeled last chunk: no prefetch outstanding afterwards
    asm volatile("s_waitcnt vmcnt(0)" ::: "memory");
    __builtin_amdgcn_s_barrier();
    __builtin_amdgcn_sched_barrier(0);
    compute(N_CHUNKS - 1, bA);

    __syncthreads();   // full drain before merge aliases the ring buffers

    // merge: 16 lanes x top-2 = 32 entries per token; stride 33 = conflict-free
    float*    mv = reinterpret_cast<float*>(smem);             // [128][33]
    unsigned* mi = reinterpret_cast<unsigned*>(smem + 16896);  // [128][33]
    #pragma unroll
    for (int r = 0; r < 8; ++r) {
        const int rt = r >> 2, q = r & 3;
        const int row = w * 32 + rt * 16 + g * 4 + q;   // C/D: row=(lane>>4)*4+reg, col=lane&15
        mv[row * 33 + cl * 2 + 0] = tv0[r];  mi[row * 33 + cl * 2 + 0] = ti0[r];
        mv[row * 33 + cl * 2 + 1] = tv1[r];  mi[row * 33 + cl * 2 + 1] = ti1[r];
    }
    __syncthreads();
    if (tid < BT) {
        const float*    v  = mv + tid * 33;
        const unsigned* ii = mi + tid * 33;
        float vmin = v[0]; unsigned imin = ii[0];
        for (int j2 = 1; j2 < 32; ++j2) {
            const float vv = v[j2]; const unsigned ij = ii[j2];
            if (vv < vmin || (vv == vmin && ij < imin)) { vmin = vv; imin = ij; }
        }
        unsigned lst[7]; lst[0] = imin; int cnt = 1;
        const float lim = vmin + THR;
        for (int j2 = 0; j2 < 32; ++j2) {
            const unsigned ij = ii[j2];
            if (v[j2] <= lim && ij != imin && cnt < 7) lst[cnt++] = ij;
        }
        unsigned* cp = cand + (size_t)(t0 + tid) * 8;
        cp[0] = (unsigned)cnt;
        #pragma unroll
        for (int j2 = 0; j2 < 7; ++j2) cp[1 + j2] = (j2 < cnt) ? lst[j2] : imin;
    }
}

// ---------------- K2: exact fp32 rescue + gather + straight-through + commit ----------------
__global__ __launch_bounds__(256) void rescue_kernel(
    const float* __restrict__ x, const float* __restrict__ emb,
    const float* __restrict__ e2, const unsigned* __restrict__ cand,
    float* __restrict__ out_q, float* __restrict__ out_inds,
    unsigned* __restrict__ counts, float* __restrict__ cparts)
{
    const int tid = threadIdx.x, w = tid >> 6, lane = tid & 63;
    const int t = blockIdx.x * 4 + w;

    const float4 xv = *reinterpret_cast<const float4*>(x + (size_t)t * DIM + lane * 4);

    const unsigned* cp = cand + (size_t)t * 8;
    const int cnt = (int)cp[0];
    unsigned bi;
    if (cnt == 1) {
        bi = cp[1];            // single candidate IS the argmin — no arithmetic needed
    } else {
        float s = __fmul_rn(xv.x, xv.x);
        s = __fadd_rn(s, __fmul_rn(xv.y, xv.y));
        s = __fadd_rn(s, __fmul_rn(xv.z, xv.z));
        s = __fadd_rn(s, __fmul_rn(xv.w, xv.w));
        #pragma unroll
        for (int off = 32; off; off >>= 1) s = __fadd_rn(s, __shfl_xor(s, off));
        const float x2t = s;

        const int cn = min(cnt, 7);
        float bd = FLT_MAX; bi = 0xFFFFFFFFu;
        for (int cix = 0; cix < cn; ++cix) {
            const unsigned ci = cp[1 + cix];
            const float4 ev = *reinterpret_cast<const float4*>(emb + (size_t)ci * DIM + lane * 4);
            float p = __fmul_rn(xv.x, ev.x);
            p = fmaf(xv.y, ev.y, p);
            p = fmaf(xv.z, ev.z, p);
            p = fmaf(xv.w, ev.w, p);
            #pragma unroll
            for (int off = 32; off; off >>= 1) p = __fadd_rn(p, __shfl_xor(p, off));
            const float d = __fsub_rn(__fadd_rn(e2[ci], x2t), __fmul_rn(2.0f, p));
            if (d < bd || (d == bd && ci < bi)) { bd = d; bi = ci; }
        }
    }

    const float4 qv = *reinterpret_cast<const float4*>(emb + (size_t)bi * DIM + lane * 4);
    float4 o;
    o.x = __fadd_rn(xv.x, __fsub_rn(qv.x, xv.x));
    o.y = __fadd_rn(xv.y, __fsub_rn(qv.y, xv.y));
    o.z = __fadd_rn(xv.z, __fsub_rn(qv.z, xv.z));
    o.w = __fadd_rn(xv.w, __fsub_rn(qv.w, xv.w));
    *reinterpret_cast<float4*>(out_q + (size_t)t * DIM + lane * 4) = o;

    float cl2 = 0.0f, dx;
    dx = __fsub_rn(xv.x, qv.x); cl2 = fmaf(dx, dx, cl2);
    dx = __fsub_rn(xv.y, qv.y); cl2 = fmaf(dx, dx, cl2);
    dx = __fsub_rn(xv.z, qv.z); cl2 = fmaf(dx, dx, cl2);
    dx = __fsub_rn(xv.w, qv.w); cl2 = fmaf(dx, dx, cl2);
    #pragma unroll
    for (int off = 32; off; off >>= 1) cl2 += __shfl_xor(cl2, off);

    __shared__ float wp[4];
    if (lane == 0) {
        out_inds[t] = (float)bi;
        atomicAdd(&counts[bi], 1u);
        wp[w] = cl2;
    }
    __syncthreads();
    if (tid == 0) cparts[blockIdx.x] = (wp[0] + wp[1]) + (wp[2] + wp[3]);
}

// ---------------- K3: stats scalars ----------------
__global__ void stats_kernel(const unsigned* __restrict__ counts,
                             const float* __restrict__ cparts,
                             float* __restrict__ out)
{
    const int tid = threadIdx.x, lane = tid & 63, wv = tid >> 6;  // 1024 threads
    const float c = (float)counts[tid];
    float u = (c >= 1.0f) ? 1.0f : 0.0f;
    const float p = c / 65536.0f;
    float e = p * logf(p + 1e-10f);
    double cs = 0.0;
    #pragma unroll
    for (int j = 0; j < 16; ++j) cs += (double)cparts[tid * 16 + j];
    #pragma unroll
    for (int off = 32; off; off >>= 1) {
        u  += __shfl_xor(u, off);
        e  += __shfl_xor(e, off);
        cs += __shfl_xor(cs, off);
    }
    __shared__ float  su[16], se[16];
    __shared__ double sc[16];
    if (lane == 0) { su[wv] = u; se[wv] = e; sc[wv] = cs; }
    __syncthreads();
    if (tid == 0) {
        float U = 0.0f, E = 0.0f; double C = 0.0;
        for (int wj = 0; wj < 16; ++wj) { U += su[wj]; E += se[wj]; C += sc[wj]; }
        out[16842752] = U;
        out[16842753] = expf(-E);
        out[16842754] = (float)(C / 16777216.0);
    }
}

extern "C" void kernel_launch(void* const* d_in, const int* in_sizes, int n_in,
                              void* d_out, int out_size, void* d_ws, size_t ws_size,
                              hipStream_t stream) {
    const float* x   = (const float*)d_in[0];
    const float* emb = (const float*)d_in[1];
    float* out = (float*)d_out;

    char* ws = (char*)d_ws;
    float*          e2     = (float*)ws;                        // 4 KB
    unsigned short* eb     = (unsigned short*)(ws + 4096);      // 512 KB (frag-tiled bf16)
    unsigned*       cand   = (unsigned*)(ws + 528384);          // 2 MB  (8 u32 / token)
    unsigned*       counts = (unsigned*)(ws + 2625536);         // 4 KB
    float*          cparts = (float*)(ws + 2629632);            // 64 KB (16384 f32)

    float* out_q    = out;                   // [0, 16777216)
    float* out_inds = out + 16777216;        // [16777216, 16842752)

    prep_emb_kernel<<<256, 256, 0, stream>>>(emb, eb, e2, counts);
    prefilter_kernel<<<N_TOK / BT, 256, 0, stream>>>(x, eb, e2, cand);
    rescue_kernel<<<N_TOK / 4, 256, 0, stream>>>(x, emb, e2, cand, out_q, out_inds, counts, cparts);
    stats_kernel<<<1, 1024, 0, stream>>>(counts, cparts, out);
}